// Round 15
// baseline (307.426 us; speedup 1.0000x reference)
//
#include <hip/hip_runtime.h>
#include <float.h>
#include <math.h>

#define B_ 4
#define L_ 4096
#define H_ 8
#define D_ 64
#define S_ 45      // sample_k == u == 45
#define KC_ 16     // k-chunks for attention pass
#define KCH_ 256   // k per chunk
#define SCALE 0.125f

typedef __attribute__((ext_vector_type(8))) short short8;
typedef __attribute__((ext_vector_type(4))) float float4v;

__device__ __forceinline__ ushort f2bf(float x) {
  unsigned u = __float_as_uint(x);
  return (ushort)((u + 0x7FFFu + ((u >> 16) & 1u)) >> 16);
}

// swizzled ushort index: row-major rows of rowb bytes, 16B slots XORed by row&m
__device__ __forceinline__ int swz_us(int row, int col_b, int rowb, int m) {
  int slot = (col_b >> 4) ^ (row & m);
  return row * (rowb >> 1) + (slot << 3) + ((col_b & 15) >> 1);
}

__device__ __forceinline__ unsigned ordf(float f) {
  unsigned u = __float_as_uint(f);
  return (u & 0x80000000u) ? ~u : (u | 0x80000000u);
}

// ================= kA: gather + csum_chunks + cumsum-write ====================
// within<128: R12-proven 2-head time-phased gather (CLOSED at line-throughput
//   roofline ~100us).
// within>=128, grp<64: csum_chunks producer; signals ctr[bh] (release).
// within>=128, grp>=64: cumsum-write consumer; spins on ctr[bh]==16 (acquire),
//   self-computes carry from chunk sums (no scan kernel). Writes ALL rows;
//   kTail's finalize overwrites the 45 scatter rows per bh afterwards.
//   Producers are at dispatch idx < 8704, consumers >= 8704; spinners (512)
//   << resident capacity -> no deadlock. kA uses 7% HBM -> write stream hides.
__global__ __launch_bounds__(256) void kA(
    const float* __restrict__ Q, const float* __restrict__ K,
    const float* __restrict__ V, const int* __restrict__ idxs,
    float* __restrict__ M, float* __restrict__ cs,
    float* __restrict__ out, int* __restrict__ ctr)
{
  int blk = blockIdx.x;
  int grp = blk / 136, within = blk % 136;
  int tid = threadIdx.x;
  int w = tid >> 6, lane = tid & 63;

  if (within >= 128) {
    if (grp < 64) {
      // ---- csum_chunks producer (R12-proven) ----
      int cblk = grp * 8 + (within - 128);     // 0..511
      int bh = cblk >> 4, cg = cblk & 15;
      int b = bh >> 3, h = bh & 7;
      int t = lane & 15, rg = lane >> 4;
      int c = cg * 4 + w;
      int l0 = c * 64;
      const float4* V4 = (const float4*)V;
      float4 acc = make_float4(0.f, 0.f, 0.f, 0.f);
      for (int step = 0; step < 16; ++step) {
        int l = l0 + step * 4 + rg;
        float4 v = V4[((size_t)(b * L_ + l) * H_ + h) * 16 + t];
        acc.x += v.x; acc.y += v.y; acc.z += v.z; acc.w += v.w;
      }
      acc.x += __shfl_xor(acc.x, 16, 64); acc.y += __shfl_xor(acc.y, 16, 64);
      acc.z += __shfl_xor(acc.z, 16, 64); acc.w += __shfl_xor(acc.w, 16, 64);
      acc.x += __shfl_xor(acc.x, 32, 64); acc.y += __shfl_xor(acc.y, 32, 64);
      acc.z += __shfl_xor(acc.z, 32, 64); acc.w += __shfl_xor(acc.w, 32, 64);
      if (rg == 0)
        ((float4*)cs)[((size_t)bh * 64 + c) * 16 + t] = acc;
      __syncthreads();
      if (tid == 0) {
        __threadfence();
        atomicAdd(&ctr[bh], 1);
      }
      return;
    }
    // ---- cumsum-write consumer ----
    int wblk = (grp - 64) * 8 + (within - 128);  // 0..511
    int bh = wblk >> 4, cg2 = wblk & 15;
    if (tid == 0) {
      while (atomicAdd(&ctr[bh], 0) < 16) { }
    }
    __syncthreads();
    __threadfence();
    int b = bh >> 3, h = bh & 7;
    int t = lane & 15, rg = lane >> 4;
    int c = cg2 * 4 + w;
    int l0 = c * 64;
    const float4* cs4 = (const float4*)cs;
    float4 carry = make_float4(0.f, 0.f, 0.f, 0.f);
    for (int cc = 0; cc < c; ++cc) {
      float4 x = cs4[((size_t)bh * 64 + cc) * 16 + t];
      carry.x += x.x; carry.y += x.y; carry.z += x.z; carry.w += x.w;
    }
    const float4* V4 = (const float4*)V;
    float4* O4 = (float4*)out;
    for (int step = 0; step < 16; ++step) {
      int l = l0 + step * 4 + rg;
      float4 v = V4[((size_t)(b * L_ + l) * H_ + h) * 16 + t];
      float4 u;
      u.x = __shfl_up(v.x, 16, 64); u.y = __shfl_up(v.y, 16, 64);
      u.z = __shfl_up(v.z, 16, 64); u.w = __shfl_up(v.w, 16, 64);
      if (rg >= 1) { v.x += u.x; v.y += u.y; v.z += u.z; v.w += u.w; }
      u.x = __shfl_up(v.x, 32, 64); u.y = __shfl_up(v.y, 32, 64);
      u.z = __shfl_up(v.z, 32, 64); u.w = __shfl_up(v.w, 32, 64);
      if (rg >= 2) { v.x += u.x; v.y += u.y; v.z += u.z; v.w += u.w; }
      float4 o;
      o.x = carry.x + v.x; o.y = carry.y + v.y;
      o.z = carry.z + v.z; o.w = carry.w + v.w;
      O4[((size_t)bh * L_ + l) * 16 + t] = o;
      carry.x += __shfl(v.x, 48 + t, 64); carry.y += __shfl(v.y, 48 + t, 64);
      carry.z += __shfl(v.z, 48 + t, 64); carry.w += __shfl(v.w, 48 + t, 64);
    }
    return;
  }

  // ---- gather (R12-proven) ----
  int kblk = grp * 128 + within;        // 0..16383; kblk%8 == blk%8 (XCD pin)
  int phase = kblk >> 13;               // 0: b in {0,1}; 1: b in {2,3}
  int pblk = kblk & 8191;
  int g = pblk & 7;                     // XCD-pinned group within phase
  int b = (g >> 2) + phase * 2;
  int hq = g & 3;                       // head pair hq*2, hq*2+1
  int chunk = pblk >> 3;                // 0..1023
  int l = chunk * 4 + w;                // this wave's query
  int t31 = lane & 31;
  int half = lane >> 5;

  const float4* qp =
      (const float4*)(Q + ((size_t)(b * L_ + l) * H_ + hq * 2) * D_);
  float4 qv = qp[t31];

  int s = lane < S_ ? lane : S_ - 1;
  int idxall = idxs[l * S_ + s];

  float vmax = -FLT_MAX, vsum = 0.f;
  #pragma unroll
  for (int c = 0; c < 3; ++c) {
    int kidx[6];
    #pragma unroll
    for (int jj = 0; jj < 6; ++jj)
      kidx[jj] = __shfl(idxall, (c * 6 + jj) * 2 + half, 64);
    float4 kv[6];
    #pragma unroll
    for (int jj = 0; jj < 6; ++jj)
      kv[jj] = ((const float4*)(K +
          ((size_t)(b * L_ + kidx[jj]) * H_ + hq * 2) * D_))[t31];
    #pragma unroll
    for (int jj = 0; jj < 6; ++jj) {
      float p = qv.x * kv[jj].x;
      p = fmaf(qv.y, kv[jj].y, p);
      p = fmaf(qv.z, kv[jj].z, p);
      p = fmaf(qv.w, kv[jj].w, p);
      p += __shfl_xor(p, 1, 64);
      p += __shfl_xor(p, 2, 64);
      p += __shfl_xor(p, 4, 64);
      p += __shfl_xor(p, 8, 64);
      vmax = fmaxf(vmax, p);
      vsum += p;
    }
  }
  {
    int kidx[5];
    #pragma unroll
    for (int jj = 0; jj < 5; ++jj) {
      int s2 = (18 + jj) * 2 + half;          // 36..45
      kidx[jj] = __shfl(idxall, s2 > 44 ? 44 : s2, 64);
    }
    float4 kv[5];
    #pragma unroll
    for (int jj = 0; jj < 5; ++jj)
      kv[jj] = ((const float4*)(K +
          ((size_t)(b * L_ + kidx[jj]) * H_ + hq * 2) * D_))[t31];
    #pragma unroll
    for (int jj = 0; jj < 5; ++jj) {
      float p = qv.x * kv[jj].x;
      p = fmaf(qv.y, kv[jj].y, p);
      p = fmaf(qv.z, kv[jj].z, p);
      p = fmaf(qv.w, kv[jj].w, p);
      p += __shfl_xor(p, 1, 64);
      p += __shfl_xor(p, 2, 64);
      p += __shfl_xor(p, 4, 64);
      p += __shfl_xor(p, 8, 64);
      bool dup = (jj == 4) && (half == 1);    // sample 45 -> clamped dup
      vmax = fmaxf(vmax, p);
      if (!dup) vsum += p;
    }
  }
  vmax = fmaxf(vmax, __shfl_xor(vmax, 32, 64));
  vsum += __shfl_xor(vsum, 32, 64);
  if ((lane & 15) == 0 && half == 0) {
    int h = hq * 2 + (lane >> 4);
    M[(size_t)(b * H_ + h) * L_ + l] = vmax - vsum * (1.0f / L_);
  }
}

// ================= kTail: topk + MFMA attention + last-block finalize =========
// blocks 0..31: topk per bh; sets flag[bh] (release).
// blocks 32..543: attention. K->LDS and V->regs staged BEFORE spinning on
//   flag[bh] (staging overlaps topk). The 16th finishing kc-block per bh
//   (atomic ticket ctr2) runs finalize inline (cut already holds mtop).
__global__ __launch_bounds__(256) void kTail(
    const float* __restrict__ Q, const float* __restrict__ K,
    const float* __restrict__ V, const float* __restrict__ M,
    int* __restrict__ mtop, float* __restrict__ lpart,
    float* __restrict__ updp, float* __restrict__ out,
    int* __restrict__ flag, int* __restrict__ ctr2)
{
  __shared__ __align__(16) ushort Ks[256 * 64];   // 32 KB; reused as Vt[64][256]
  __shared__ __align__(16) ushort Qs[48 * 64];    // 6 KB
  __shared__ __align__(16) ushort Ps[48 * 256];   // 24 KB (topk: cand overlay)
  __shared__ float lred[4][48];
  __shared__ int   cut[48];
  __shared__ int   doFin;

  int blk = blockIdx.x;
  int tid = threadIdx.x;
  int w = tid >> 6, lane = tid & 63;

  if (blk < 32) {
    // ---- topk (R12-proven), cand overlaid on Ps ----
    unsigned long long (*cand)[S_] = (unsigned long long (*)[S_])Ps;
    int bh = blk;
    const float* Mp = M + (size_t)bh * L_;
    unsigned long long key[16];
    #pragma unroll
    for (int j = 0; j < 16; ++j) {
      int gi = w * 1024 + j * 64 + lane;
      key[j] = ((unsigned long long)ordf(Mp[gi]) << 32) | (unsigned)(~gi);
    }
    for (int it = 0; it < S_; ++it) {
      unsigned long long loc = key[0];
      #pragma unroll
      for (int j = 1; j < 16; ++j) loc = key[j] > loc ? key[j] : loc;
      unsigned long long best = loc;
      #pragma unroll
      for (int m = 32; m >= 1; m >>= 1) {
        unsigned long long o = __shfl_xor(best, m, 64);
        best = o > best ? o : best;
      }
      if (loc == best) {
        #pragma unroll
        for (int j = 0; j < 16; ++j) if (key[j] == best) key[j] = 0ull;
      }
      if (lane == 0) cand[w][it] = best;
    }
    __syncthreads();
    if (w == 0) {
      unsigned long long k2[3];
      #pragma unroll
      for (int j = 0; j < 3; ++j) {
        int c = j * 64 + lane;
        k2[j] = (c < 4 * S_) ? cand[c / S_][c % S_] : 0ull;
      }
      for (int it = 0; it < S_; ++it) {
        unsigned long long loc = k2[0];
        loc = k2[1] > loc ? k2[1] : loc;
        loc = k2[2] > loc ? k2[2] : loc;
        unsigned long long best = loc;
        #pragma unroll
        for (int m = 32; m >= 1; m >>= 1) {
          unsigned long long o = __shfl_xor(best, m, 64);
          best = o > best ? o : best;
        }
        if (loc == best) {
          #pragma unroll
          for (int j = 0; j < 3; ++j) if (k2[j] == best) k2[j] = 0ull;
        }
        if (lane == 0) mtop[bh * S_ + it] = (int)(~(unsigned)(best & 0xFFFFFFFFu));
      }
      if (lane == 0) {
        __threadfence();
        atomicExch(&flag[bh], 1);
      }
    }
    return;
  }

  // ---- attention ----
  int ablk = blk - 32;                    // 0..511; ablk%8 == blk%8
  int kc = ablk >> 5;
  int r5 = ablk & 31;
  int bh = ((r5 & 7) << 2) | (r5 >> 3);   // bh>>2 == ablk&7 -> XCD pin as kA
  int b = bh >> 3, h = bh & 7;
  int l15 = lane & 15, l4 = lane >> 4;

  // T14: V loads issued early (consumed after P) -> overlap with topk/K-stage
  float4 vreg[16];
  {
    const float4* vp =
        (const float4*)(V + ((size_t)(b * L_ + kc * KCH_ + tid) * H_ + h) * D_);
    #pragma unroll
    for (int c = 0; c < 16; ++c) vreg[c] = vp[c];
  }
  // K-stage (independent of mtop) before the spin
  {
    const float4* kp =
        (const float4*)(K + ((size_t)(b * L_ + kc * KCH_ + tid) * H_ + h) * D_);
    #pragma unroll
    for (int c = 0; c < 8; ++c) {
      float4 a = kp[2 * c], bb = kp[2 * c + 1];
      uint4 pk;
      pk.x = f2bf(a.x) | ((unsigned)f2bf(a.y) << 16);
      pk.y = f2bf(a.z) | ((unsigned)f2bf(a.w) << 16);
      pk.z = f2bf(bb.x) | ((unsigned)f2bf(bb.y) << 16);
      pk.w = f2bf(bb.z) | ((unsigned)f2bf(bb.w) << 16);
      *(uint4*)&Ks[swz_us(tid, c * 16, 128, 7)] = pk;
    }
  }
  // wait for topk of this bh
  if (tid == 0) {
    while (atomicAdd(&flag[bh], 0) == 0) { }
  }
  __syncthreads();
  __threadfence();

  if (tid < 48) cut[tid] = (tid < S_) ? mtop[bh * S_ + tid] : -1;
  __syncthreads();
  for (int i = tid; i < 48 * 8; i += 256) {
    int row = i >> 3, c = i & 7;
    uint4 pk = make_uint4(0, 0, 0, 0);
    if (row < S_) {
      const float4* qp =
          (const float4*)(Q + ((size_t)(b * L_ + cut[row]) * H_ + h) * D_);
      float4 a = qp[2 * c], bb = qp[2 * c + 1];
      pk.x = f2bf(a.x) | ((unsigned)f2bf(a.y) << 16);
      pk.y = f2bf(a.z) | ((unsigned)f2bf(a.w) << 16);
      pk.z = f2bf(bb.x) | ((unsigned)f2bf(bb.y) << 16);
      pk.w = f2bf(bb.z) | ((unsigned)f2bf(bb.w) << 16);
    }
    *(uint4*)&Qs[swz_us(row, c * 16, 128, 7)] = pk;
  }
  __syncthreads();

  float4v accS[3][4];
  #pragma unroll
  for (int mt = 0; mt < 3; ++mt)
    #pragma unroll
    for (int nt = 0; nt < 4; ++nt)
      accS[mt][nt] = (float4v){0.f, 0.f, 0.f, 0.f};
  #pragma unroll
  for (int ks = 0; ks < 2; ++ks) {
    short8 afr[3];
    #pragma unroll
    for (int mt = 0; mt < 3; ++mt)
      afr[mt] = *(const short8*)&Qs[swz_us(mt * 16 + l15, ks * 64 + l4 * 16, 128, 7)];
    #pragma unroll
    for (int nt = 0; nt < 4; ++nt) {
      short8 bfr = *(const short8*)
          &Ks[swz_us(w * 64 + nt * 16 + l15, ks * 64 + l4 * 16, 128, 7)];
      #pragma unroll
      for (int mt = 0; mt < 3; ++mt)
        accS[mt][nt] = __builtin_amdgcn_mfma_f32_16x16x32_bf16(
            afr[mt], bfr, accS[mt][nt], 0, 0, 0);
    }
  }

  #pragma unroll
  for (int mt = 0; mt < 3; ++mt) {
    #pragma unroll
    for (int j = 0; j < 4; ++j) {
      int row = mt * 16 + l4 * 4 + j;
      int ct = cut[row];
      float rs = 0.f;
      #pragma unroll
      for (int nt = 0; nt < 4; ++nt) {
        int col = w * 64 + nt * 16 + l15;
        int kg = kc * KCH_ + col;
        float e = (kg <= ct) ? __expf(accS[mt][nt][j] * SCALE) : 0.f;
        rs += e;
        Ps[swz_us(row, col * 2, 512, 15)] = f2bf(e);
      }
      rs += __shfl_xor(rs, 1, 64);
      rs += __shfl_xor(rs, 2, 64);
      rs += __shfl_xor(rs, 4, 64);
      rs += __shfl_xor(rs, 8, 64);
      if (l15 == 0) lred[w][row] = rs;
    }
  }
  __syncthreads();

  if (tid < S_)
    lpart[((size_t)(bh * KC_ + kc)) * S_ + tid] =
        lred[0][tid] + lred[1][tid] + lred[2][tid] + lred[3][tid];

  // V-stage: registers -> LDS
  #pragma unroll
  for (int c = 0; c < 16; ++c) {
    float4 v = vreg[c];
    int d0 = c * 4;
    Ks[swz_us(d0 + 0, tid * 2, 512, 15)] = f2bf(v.x);
    Ks[swz_us(d0 + 1, tid * 2, 512, 15)] = f2bf(v.y);
    Ks[swz_us(d0 + 2, tid * 2, 512, 15)] = f2bf(v.z);
    Ks[swz_us(d0 + 3, tid * 2, 512, 15)] = f2bf(v.w);
  }
  __syncthreads();

  float4v accU[3];
  #pragma unroll
  for (int i = 0; i < 3; ++i) accU[i] = (float4v){0.f, 0.f, 0.f, 0.f};
  #pragma unroll
  for (int ks = 0; ks < 8; ++ks) {
    #pragma unroll
    for (int i = 0; i < 3; ++i) {
      int pi = w * 3 + i, mt = pi >> 2, nt = pi & 3;
      short8 afr = *(const short8*)
          &Ps[swz_us(mt * 16 + l15, ks * 64 + l4 * 16, 512, 15)];
      short8 bfr = *(const short8*)
          &Ks[swz_us(nt * 16 + l15, ks * 64 + l4 * 16, 512, 15)];
      accU[i] = __builtin_amdgcn_mfma_f32_16x16x32_bf16(afr, bfr, accU[i], 0, 0, 0);
    }
  }
  float* up = updp + ((size_t)(bh * KC_ + kc)) * (S_ * D_);
  #pragma unroll
  for (int i = 0; i < 3; ++i) {
    int pi = w * 3 + i, mt = pi >> 2, nt = pi & 3;
    #pragma unroll
    for (int j = 0; j < 4; ++j) {
      int row = mt * 16 + l4 * 4 + j;
      if (row < S_) up[row * D_ + nt * 16 + l15] = accU[i][j];
    }
  }

  // ---- last-block-per-bh finalize ----
  __syncthreads();
  if (tid == 0) {
    __threadfence();
    int old = atomicAdd(&ctr2[bh], 1);
    doFin = (old == KC_ - 1) ? 1 : 0;
  }
  __syncthreads();
  if (doFin) {
    __threadfence();
    float* linvp = lred[0];     // free after lpart write
    if (tid < S_) {
      float l = 0.f;
      for (int kcc = 0; kcc < KC_; ++kcc)
        l += lpart[(size_t)(bh * KC_ + kcc) * S_ + tid];
      linvp[tid] = 1.0f / l;
    }
    __syncthreads();
    for (int i = tid; i < S_ * D_; i += 256) {
      int r = i >> 6, d = i & 63;
      float u = 0.f;
      for (int kcc = 0; kcc < KC_; ++kcc)
        u += updp[((size_t)(bh * KC_ + kcc)) * (S_ * D_) + i];
      out[((size_t)bh * L_ + cut[r]) * D_ + d] = u * linvp[r];
    }
  }
}

extern "C" void kernel_launch(void* const* d_in, const int* in_sizes, int n_in,
                              void* d_out, int out_size, void* d_ws, size_t ws_size,
                              hipStream_t stream) {
  const float* Q = (const float*)d_in[0];
  const float* K = (const float*)d_in[1];
  const float* V = (const float*)d_in[2];
  const int*   I = (const int*)d_in[3];
  float* out = (float*)d_out;
  float* ws = (float*)d_ws;

  float* M     = ws;                       // 131072 floats
  float* cs    = ws + 131072;              // 131072 floats
  float* lpart = ws + 262144;              // 32*16*45 = 23040 floats
  float* updp  = ws + 262144 + 23040;      // 32*16*45*64 = 1474560 floats
  int*   mtop  = (int*)(ws + 262144 + 23040 + 1474560);   // 1440 ints
  int*   ctr   = mtop + 1440;              // 32 ints: chunk-done per bh
  int*   flag  = ctr + 32;                 // 32 ints: topk-done per bh
  int*   ctr2  = flag + 32;                // 32 ints: attn-done per bh

  hipMemsetAsync(ctr, 0, 96 * sizeof(int), stream);
  kA<<<128 * 136, 256, 0, stream>>>(Q, K, V, I, M, cs, out, ctr);
  kTail<<<544, 256, 0, stream>>>(Q, K, V, M, mtop, lpart, updp, out, flag, ctr2);
}

// Round 17
// 226.923 us; speedup vs baseline: 1.3548x; 1.3548x over previous
//
#include <hip/hip_runtime.h>
#include <float.h>
#include <math.h>

#define B_ 4
#define L_ 4096
#define H_ 8
#define D_ 64
#define S_ 45      // sample_k == u == 45
#define KC_ 16     // k-chunks for attention pass
#define KCH_ 256   // k per chunk
#define SCALE 0.125f

typedef __attribute__((ext_vector_type(8))) short short8;
typedef __attribute__((ext_vector_type(4))) float float4v;

__device__ __forceinline__ float4 nt_load4(const float* p) {
  float4v v = __builtin_nontemporal_load((const float4v*)p);
  return make_float4(v.x, v.y, v.z, v.w);
}

__device__ __forceinline__ ushort f2bf(float x) {
  unsigned u = __float_as_uint(x);
  return (ushort)((u + 0x7FFFu + ((u >> 16) & 1u)) >> 16);
}

// swizzled ushort index: row-major rows of rowb bytes, 16B slots XORed by row&m
__device__ __forceinline__ int swz_us(int row, int col_b, int rowb, int m) {
  int slot = (col_b >> 4) ^ (row & m);
  return row * (rowb >> 1) + (slot << 3) + ((col_b & 15) >> 1);
}

__device__ __forceinline__ unsigned ordf(float f) {
  unsigned u = __float_as_uint(f);
  return (u & 0x80000000u) ? ~u : (u | 0x80000000u);
}

// ================= kA: 2-head time-phased gather + csum_chunks (R12-proven) ===
// Gather data is single-use per line -> nontemporal loads (L1-bypass hint).
// If null vs R12's 102us, the TCP line path (~26 B/cyc/CU) is the closed floor.
__global__ __launch_bounds__(256) void kA(
    const float* __restrict__ Q, const float* __restrict__ K,
    const float* __restrict__ V, const int* __restrict__ idxs,
    float* __restrict__ M, float* __restrict__ cs)
{
  int blk = blockIdx.x;
  int grp = blk / 136, within = blk % 136;
  int tid = threadIdx.x;
  int w = tid >> 6, lane = tid & 63;

  if (within >= 128) {
    if (grp >= 64) return;                   // only 512 csum blocks needed
    int cblk = grp * 8 + (within - 128);     // 0..511
    int bh = cblk >> 4, cg = cblk & 15;
    int b = bh >> 3, h = bh & 7;
    int t = lane & 15, rg = lane >> 4;
    int c = cg * 4 + w;
    int l0 = c * 64;
    float4 acc = make_float4(0.f, 0.f, 0.f, 0.f);
    for (int step = 0; step < 16; ++step) {
      int l = l0 + step * 4 + rg;
      float4 v = nt_load4(V + (((size_t)(b * L_ + l) * H_ + h) * 16 + t) * 4);
      acc.x += v.x; acc.y += v.y; acc.z += v.z; acc.w += v.w;
    }
    acc.x += __shfl_xor(acc.x, 16, 64); acc.y += __shfl_xor(acc.y, 16, 64);
    acc.z += __shfl_xor(acc.z, 16, 64); acc.w += __shfl_xor(acc.w, 16, 64);
    acc.x += __shfl_xor(acc.x, 32, 64); acc.y += __shfl_xor(acc.y, 32, 64);
    acc.z += __shfl_xor(acc.z, 32, 64); acc.w += __shfl_xor(acc.w, 32, 64);
    if (rg == 0)
      ((float4*)cs)[((size_t)bh * 64 + c) * 16 + t] = acc;
    return;
  }

  // ---- gather ----
  int kblk = grp * 128 + within;        // 0..16383; kblk%8 == blk%8 (XCD pin)
  int phase = kblk >> 13;               // 0: b in {0,1}; 1: b in {2,3}
  int pblk = kblk & 8191;
  int g = pblk & 7;                     // XCD-pinned group within phase
  int b = (g >> 2) + phase * 2;
  int hq = g & 3;                       // head pair hq*2, hq*2+1
  int chunk = pblk >> 3;                // 0..1023
  int l = chunk * 4 + w;                // this wave's query
  int t31 = lane & 31;
  int half = lane >> 5;

  const float4* qp =
      (const float4*)(Q + ((size_t)(b * L_ + l) * H_ + hq * 2) * D_);
  float4 qv = qp[t31];

  int s = lane < S_ ? lane : S_ - 1;
  int idxall = idxs[l * S_ + s];

  float vmax = -FLT_MAX, vsum = 0.f;
  #pragma unroll
  for (int c = 0; c < 3; ++c) {
    int kidx[6];
    #pragma unroll
    for (int jj = 0; jj < 6; ++jj)
      kidx[jj] = __shfl(idxall, (c * 6 + jj) * 2 + half, 64);
    float4 kv[6];
    #pragma unroll
    for (int jj = 0; jj < 6; ++jj)
      kv[jj] = nt_load4(K +
          ((size_t)(b * L_ + kidx[jj]) * H_ + hq * 2) * D_ + t31 * 4);
    #pragma unroll
    for (int jj = 0; jj < 6; ++jj) {
      float p = qv.x * kv[jj].x;
      p = fmaf(qv.y, kv[jj].y, p);
      p = fmaf(qv.z, kv[jj].z, p);
      p = fmaf(qv.w, kv[jj].w, p);
      p += __shfl_xor(p, 1, 64);
      p += __shfl_xor(p, 2, 64);
      p += __shfl_xor(p, 4, 64);
      p += __shfl_xor(p, 8, 64);
      vmax = fmaxf(vmax, p);
      vsum += p;
    }
  }
  {
    int kidx[5];
    #pragma unroll
    for (int jj = 0; jj < 5; ++jj) {
      int s2 = (18 + jj) * 2 + half;          // 36..45
      kidx[jj] = __shfl(idxall, s2 > 44 ? 44 : s2, 64);
    }
    float4 kv[5];
    #pragma unroll
    for (int jj = 0; jj < 5; ++jj)
      kv[jj] = nt_load4(K +
          ((size_t)(b * L_ + kidx[jj]) * H_ + hq * 2) * D_ + t31 * 4);
    #pragma unroll
    for (int jj = 0; jj < 5; ++jj) {
      float p = qv.x * kv[jj].x;
      p = fmaf(qv.y, kv[jj].y, p);
      p = fmaf(qv.z, kv[jj].z, p);
      p = fmaf(qv.w, kv[jj].w, p);
      p += __shfl_xor(p, 1, 64);
      p += __shfl_xor(p, 2, 64);
      p += __shfl_xor(p, 4, 64);
      p += __shfl_xor(p, 8, 64);
      bool dup = (jj == 4) && (half == 1);    // sample 45 -> clamped dup
      vmax = fmaxf(vmax, p);
      if (!dup) vsum += p;
    }
  }
  vmax = fmaxf(vmax, __shfl_xor(vmax, 32, 64));
  vsum += __shfl_xor(vsum, 32, 64);
  if ((lane & 15) == 0 && half == 0) {
    int h = hq * 2 + (lane >> 4);
    M[(size_t)(b * H_ + h) * L_ + l] = vmax - vsum * (1.0f / L_);
  }
}

// ================= kB: top-45 per (b,h) + csum_scan (R12-proven) ==============
__global__ __launch_bounds__(256) void kB(
    const float* __restrict__ M, int* __restrict__ mtop, float* __restrict__ cs)
{
  int blk = blockIdx.x;
  int tid = threadIdx.x;
  if (blk >= 32) {
    int g = (blk - 32) * 256 + tid;    // 2048 threads total
    int bh = g >> 6, d = g & 63;
    float v[64];
    #pragma unroll
    for (int c = 0; c < 64; ++c) v[c] = cs[((size_t)bh * 64 + c) * D_ + d];
    float run = 0.f;
    #pragma unroll
    for (int c = 0; c < 64; ++c) {
      float a = v[c];
      cs[((size_t)bh * 64 + c) * D_ + d] = run;
      run += a;
    }
    return;
  }
  __shared__ unsigned long long cand[4][S_];
  int bh = blk;
  int w = tid >> 6, lane = tid & 63;
  const float* Mp = M + (size_t)bh * L_;
  unsigned long long key[16];
  #pragma unroll
  for (int j = 0; j < 16; ++j) {
    int gi = w * 1024 + j * 64 + lane;
    key[j] = ((unsigned long long)ordf(Mp[gi]) << 32) | (unsigned)(~gi);
  }
  for (int it = 0; it < S_; ++it) {
    unsigned long long loc = key[0];
    #pragma unroll
    for (int j = 1; j < 16; ++j) loc = key[j] > loc ? key[j] : loc;
    unsigned long long best = loc;
    #pragma unroll
    for (int m = 32; m >= 1; m >>= 1) {
      unsigned long long o = __shfl_xor(best, m, 64);
      best = o > best ? o : best;
    }
    if (loc == best) {
      #pragma unroll
      for (int j = 0; j < 16; ++j) if (key[j] == best) key[j] = 0ull;
    }
    if (lane == 0) cand[w][it] = best;
  }
  __syncthreads();
  if (w == 0) {
    unsigned long long k2[3];
    #pragma unroll
    for (int j = 0; j < 3; ++j) {
      int c = j * 64 + lane;
      k2[j] = (c < 4 * S_) ? cand[c / S_][c % S_] : 0ull;
    }
    for (int it = 0; it < S_; ++it) {
      unsigned long long loc = k2[0];
      loc = k2[1] > loc ? k2[1] : loc;
      loc = k2[2] > loc ? k2[2] : loc;
      unsigned long long best = loc;
      #pragma unroll
      for (int m = 32; m >= 1; m >>= 1) {
        unsigned long long o = __shfl_xor(best, m, 64);
        best = o > best ? o : best;
      }
      if (loc == best) {
        #pragma unroll
        for (int j = 0; j < 3; ++j) if (k2[j] == best) k2[j] = 0ull;
      }
      if (lane == 0) mtop[bh * S_ + it] = (int)(~(unsigned)(best & 0xFFFFFFFFu));
    }
  }
}

// ================= kATT: MFMA attention partials (R12-proven, KCH=256) ========
__global__ __launch_bounds__(256) void kATT(
    const float* __restrict__ Q, const float* __restrict__ K,
    const float* __restrict__ V, const int* __restrict__ mtop,
    float* __restrict__ lpart, float* __restrict__ updp)
{
  __shared__ __align__(16) ushort Ks[256 * 64];   // 32 KB; reused as Vt[64][256]
  __shared__ __align__(16) ushort Qs[48 * 64];    // 6 KB
  __shared__ __align__(16) ushort Ps[48 * 256];   // 24 KB
  __shared__ float lred[4][48];
  __shared__ int   cut[48];

  int blk = blockIdx.x;
  int kc = blk >> 5;
  int r5 = blk & 31;
  int bh = ((r5 & 7) << 2) | (r5 >> 3);   // blk%8 == bh>>2 -> XCD pin
  int b = bh >> 3, h = bh & 7;
  int tid = threadIdx.x;
  int w = tid >> 6, lane = tid & 63;
  int l15 = lane & 15, l4 = lane >> 4;

  if (tid < 48) cut[tid] = (tid < S_) ? mtop[bh * S_ + tid] : -1;
  __syncthreads();

  {
    const float4* kp =
        (const float4*)(K + ((size_t)(b * L_ + kc * KCH_ + tid) * H_ + h) * D_);
    #pragma unroll
    for (int c = 0; c < 8; ++c) {
      float4 a = kp[2 * c], bb = kp[2 * c + 1];
      uint4 pk;
      pk.x = f2bf(a.x) | ((unsigned)f2bf(a.y) << 16);
      pk.y = f2bf(a.z) | ((unsigned)f2bf(a.w) << 16);
      pk.z = f2bf(bb.x) | ((unsigned)f2bf(bb.y) << 16);
      pk.w = f2bf(bb.z) | ((unsigned)f2bf(bb.w) << 16);
      *(uint4*)&Ks[swz_us(tid, c * 16, 128, 7)] = pk;
    }
  }
  for (int i = tid; i < 48 * 8; i += 256) {
    int row = i >> 3, c = i & 7;
    uint4 pk = make_uint4(0, 0, 0, 0);
    if (row < S_) {
      const float4* qp =
          (const float4*)(Q + ((size_t)(b * L_ + cut[row]) * H_ + h) * D_);
      float4 a = qp[2 * c], bb = qp[2 * c + 1];
      pk.x = f2bf(a.x) | ((unsigned)f2bf(a.y) << 16);
      pk.y = f2bf(a.z) | ((unsigned)f2bf(a.w) << 16);
      pk.z = f2bf(bb.x) | ((unsigned)f2bf(bb.y) << 16);
      pk.w = f2bf(bb.z) | ((unsigned)f2bf(bb.w) << 16);
    }
    *(uint4*)&Qs[swz_us(row, c * 16, 128, 7)] = pk;
  }
  __syncthreads();

  float4v accS[3][4];
  #pragma unroll
  for (int mt = 0; mt < 3; ++mt)
    #pragma unroll
    for (int nt = 0; nt < 4; ++nt)
      accS[mt][nt] = (float4v){0.f, 0.f, 0.f, 0.f};
  #pragma unroll
  for (int ks = 0; ks < 2; ++ks) {
    short8 afr[3];
    #pragma unroll
    for (int mt = 0; mt < 3; ++mt)
      afr[mt] = *(const short8*)&Qs[swz_us(mt * 16 + l15, ks * 64 + l4 * 16, 128, 7)];
    #pragma unroll
    for (int nt = 0; nt < 4; ++nt) {
      short8 bfr = *(const short8*)
          &Ks[swz_us(w * 64 + nt * 16 + l15, ks * 64 + l4 * 16, 128, 7)];
      #pragma unroll
      for (int mt = 0; mt < 3; ++mt)
        accS[mt][nt] = __builtin_amdgcn_mfma_f32_16x16x32_bf16(
            afr[mt], bfr, accS[mt][nt], 0, 0, 0);
    }
  }

  #pragma unroll
  for (int mt = 0; mt < 3; ++mt) {
    #pragma unroll
    for (int j = 0; j < 4; ++j) {
      int row = mt * 16 + l4 * 4 + j;
      int ct = cut[row];
      float rs = 0.f;
      #pragma unroll
      for (int nt = 0; nt < 4; ++nt) {
        int col = w * 64 + nt * 16 + l15;
        int kg = kc * KCH_ + col;
        float e = (kg <= ct) ? __expf(accS[mt][nt][j] * SCALE) : 0.f;
        rs += e;
        Ps[swz_us(row, col * 2, 512, 15)] = f2bf(e);
      }
      rs += __shfl_xor(rs, 1, 64);
      rs += __shfl_xor(rs, 2, 64);
      rs += __shfl_xor(rs, 4, 64);
      rs += __shfl_xor(rs, 8, 64);
      if (l15 == 0) lred[w][row] = rs;
    }
  }
  __syncthreads();

  if (tid < S_)
    lpart[((size_t)(bh * KC_ + kc)) * S_ + tid] =
        lred[0][tid] + lred[1][tid] + lred[2][tid] + lred[3][tid];

  {
    const float4* vp =
        (const float4*)(V + ((size_t)(b * L_ + kc * KCH_ + tid) * H_ + h) * D_);
    #pragma unroll
    for (int c = 0; c < 16; ++c) {
      float4 v = vp[c];
      int d0 = c * 4;
      Ks[swz_us(d0 + 0, tid * 2, 512, 15)] = f2bf(v.x);
      Ks[swz_us(d0 + 1, tid * 2, 512, 15)] = f2bf(v.y);
      Ks[swz_us(d0 + 2, tid * 2, 512, 15)] = f2bf(v.z);
      Ks[swz_us(d0 + 3, tid * 2, 512, 15)] = f2bf(v.w);
    }
  }
  __syncthreads();

  float4v accU[3];
  #pragma unroll
  for (int i = 0; i < 3; ++i) accU[i] = (float4v){0.f, 0.f, 0.f, 0.f};
  #pragma unroll
  for (int ks = 0; ks < 8; ++ks) {
    #pragma unroll
    for (int i = 0; i < 3; ++i) {
      int pi = w * 3 + i, mt = pi >> 2, nt = pi & 3;
      short8 afr = *(const short8*)
          &Ps[swz_us(mt * 16 + l15, ks * 64 + l4 * 16, 512, 15)];
      short8 bfr = *(const short8*)
          &Ks[swz_us(nt * 16 + l15, ks * 64 + l4 * 16, 512, 15)];
      accU[i] = __builtin_amdgcn_mfma_f32_16x16x32_bf16(afr, bfr, accU[i], 0, 0, 0);
    }
  }
  float* up = updp + ((size_t)(bh * KC_ + kc)) * (S_ * D_);
  #pragma unroll
  for (int i = 0; i < 3; ++i) {
    int pi = w * 3 + i, mt = pi >> 2, nt = pi & 3;
    #pragma unroll
    for (int j = 0; j < 4; ++j) {
      int row = mt * 16 + l4 * 4 + j;
      if (row < S_) up[row * D_ + nt * 16 + l15] = accU[i][j];
    }
  }
}

// ================= kWD: csum_write (skip scatter rows) + finalize (R12) =======
__global__ __launch_bounds__(256) void kWD(
    const float* __restrict__ V, const float* __restrict__ cs,
    const float* __restrict__ lpart, const float* __restrict__ updp,
    const int* __restrict__ mtop, float* __restrict__ out)
{
  int blk = blockIdx.x;
  int tid = threadIdx.x;

  if (blk >= 512) {
    // ---- finalize ----
    __shared__ float linv[S_];
    __shared__ int   mt[S_];
    int bh = blk - 512;
    if (tid < S_) {
      float l = 0.f;
      for (int kc = 0; kc < KC_; ++kc) l += lpart[(size_t)(bh * KC_ + kc) * S_ + tid];
      linv[tid] = 1.0f / l;
      mt[tid] = mtop[bh * S_ + tid];
    }
    __syncthreads();
    for (int i = tid; i < S_ * D_; i += 256) {
      int r = i >> 6, d = i & 63;
      float u = 0.f;
      for (int kc = 0; kc < KC_; ++kc)
        u += updp[((size_t)(bh * KC_ + kc)) * (S_ * D_) + i];
      out[((size_t)bh * L_ + mt[r]) * D_ + d] = u * linv[r];
    }
    return;
  }

  // ---- csum_write with scatter-row skip ----
  __shared__ unsigned bits[8];   // 256-bit bitmap for this block's row window
  int bh = blk >> 4, cg2 = blk & 15;
  int base = cg2 * 256;
  if (tid < 8) bits[tid] = 0u;
  __syncthreads();
  if (tid < S_) {
    int r = mtop[bh * S_ + tid] - base;
    if ((unsigned)r < 256u) atomicOr(&bits[r >> 5], 1u << (r & 31));
  }
  __syncthreads();

  int b = bh >> 3, h = bh & 7;
  int w = tid >> 6, lane = tid & 63;
  int t = lane & 15, rg = lane >> 4;
  int c = cg2 * 4 + w;
  int l0 = c * 64;
  float4* O4 = (float4*)out;
  float4 carry = ((const float4*)cs)[((size_t)bh * 64 + c) * 16 + t];
  for (int step = 0; step < 16; ++step) {
    int l = l0 + step * 4 + rg;
    float4 v = nt_load4(V + (((size_t)(b * L_ + l) * H_ + h) * 16 + t) * 4);
    float4 u;
    u.x = __shfl_up(v.x, 16, 64); u.y = __shfl_up(v.y, 16, 64);
    u.z = __shfl_up(v.z, 16, 64); u.w = __shfl_up(v.w, 16, 64);
    if (rg >= 1) { v.x += u.x; v.y += u.y; v.z += u.z; v.w += u.w; }
    u.x = __shfl_up(v.x, 32, 64); u.y = __shfl_up(v.y, 32, 64);
    u.z = __shfl_up(v.z, 32, 64); u.w = __shfl_up(v.w, 32, 64);
    if (rg >= 2) { v.x += u.x; v.y += u.y; v.z += u.z; v.w += u.w; }
    int wl = l - base;
    if (!((bits[wl >> 5] >> (wl & 31)) & 1u)) {
      float4 o;
      o.x = carry.x + v.x; o.y = carry.y + v.y;
      o.z = carry.z + v.z; o.w = carry.w + v.w;
      O4[((size_t)bh * L_ + l) * 16 + t] = o;
    }
    carry.x += __shfl(v.x, 48 + t, 64); carry.y += __shfl(v.y, 48 + t, 64);
    carry.z += __shfl(v.z, 48 + t, 64); carry.w += __shfl(v.w, 48 + t, 64);
  }
}

extern "C" void kernel_launch(void* const* d_in, const int* in_sizes, int n_in,
                              void* d_out, int out_size, void* d_ws, size_t ws_size,
                              hipStream_t stream) {
  const float* Q = (const float*)d_in[0];
  const float* K = (const float*)d_in[1];
  const float* V = (const float*)d_in[2];
  const int*   I = (const int*)d_in[3];
  float* out = (float*)d_out;
  float* ws = (float*)d_ws;

  float* M     = ws;                       // 131072 floats
  float* cs    = ws + 131072;              // 131072 floats
  float* lpart = ws + 262144;              // 32*16*45 = 23040 floats
  float* updp  = ws + 262144 + 23040;      // 32*16*45*64 = 1474560 floats
  int*   mtop  = (int*)(ws + 262144 + 23040 + 1474560);   // 1440 ints

  kA<<<128 * 136, 256, 0, stream>>>(Q, K, V, I, M, cs);
  kB<<<40, 256, 0, stream>>>(M, mtop, cs);
  kATT<<<B_ * H_ * KC_, 256, 0, stream>>>(Q, K, V, mtop, lpart, updp);
  kWD<<<544, 256, 0, stream>>>(V, cs, lpart, updp, mtop, out);
}

// Round 18
// 174.834 us; speedup vs baseline: 1.7584x; 1.2979x over previous
//
#include <hip/hip_runtime.h>
#include <float.h>
#include <math.h>

#define B_ 4
#define L_ 4096
#define H_ 8
#define D_ 64
#define S_ 45      // sample_k == u == 45
#define KC_ 16     // k-chunks for attention pass
#define KCH_ 256   // k per chunk
#define SCALE 0.125f

typedef __attribute__((ext_vector_type(8))) short short8;
typedef __attribute__((ext_vector_type(4))) float float4v;

__device__ __forceinline__ ushort f2bf(float x) {
  unsigned u = __float_as_uint(x);
  return (ushort)((u + 0x7FFFu + ((u >> 16) & 1u)) >> 16);
}

// swizzled ushort index: row-major rows of rowb bytes, 16B slots XORed by row&m
__device__ __forceinline__ int swz_us(int row, int col_b, int rowb, int m) {
  int slot = (col_b >> 4) ^ (row & m);
  return row * (rowb >> 1) + (slot << 3) + ((col_b & 15) >> 1);
}

__device__ __forceinline__ unsigned ordf(float f) {
  unsigned u = __float_as_uint(f);
  return (u & 0x80000000u) ? ~u : (u | 0x80000000u);
}

// ================= kA: 2-head time-phased gather + csum_chunks (R12-proven) ===
// CLOSED: at per-CU vector-memory line-throughput roofline (~23.6M lines,
// ~2.5 cyc/line/CU ~= 100us). Duration invariant to residency/MLP/occupancy;
// nontemporal hint (R17) regresses by killing L2 reuse.
__global__ __launch_bounds__(256) void kA(
    const float* __restrict__ Q, const float* __restrict__ K,
    const float* __restrict__ V, const int* __restrict__ idxs,
    float* __restrict__ M, float* __restrict__ cs)
{
  int blk = blockIdx.x;
  int grp = blk / 136, within = blk % 136;
  int tid = threadIdx.x;
  int w = tid >> 6, lane = tid & 63;

  if (within >= 128) {
    if (grp >= 64) return;                   // only 512 csum blocks needed
    int cblk = grp * 8 + (within - 128);     // 0..511
    int bh = cblk >> 4, cg = cblk & 15;
    int b = bh >> 3, h = bh & 7;
    int t = lane & 15, rg = lane >> 4;
    int c = cg * 4 + w;
    int l0 = c * 64;
    const float4* V4 = (const float4*)V;
    float4 acc = make_float4(0.f, 0.f, 0.f, 0.f);
    for (int step = 0; step < 16; ++step) {
      int l = l0 + step * 4 + rg;
      float4 v = V4[((size_t)(b * L_ + l) * H_ + h) * 16 + t];
      acc.x += v.x; acc.y += v.y; acc.z += v.z; acc.w += v.w;
    }
    acc.x += __shfl_xor(acc.x, 16, 64); acc.y += __shfl_xor(acc.y, 16, 64);
    acc.z += __shfl_xor(acc.z, 16, 64); acc.w += __shfl_xor(acc.w, 16, 64);
    acc.x += __shfl_xor(acc.x, 32, 64); acc.y += __shfl_xor(acc.y, 32, 64);
    acc.z += __shfl_xor(acc.z, 32, 64); acc.w += __shfl_xor(acc.w, 32, 64);
    if (rg == 0)
      ((float4*)cs)[((size_t)bh * 64 + c) * 16 + t] = acc;
    return;
  }

  // ---- gather ----
  int kblk = grp * 128 + within;        // 0..16383; kblk%8 == blk%8 (XCD pin)
  int phase = kblk >> 13;               // 0: b in {0,1}; 1: b in {2,3}
  int pblk = kblk & 8191;
  int g = pblk & 7;                     // XCD-pinned group within phase
  int b = (g >> 2) + phase * 2;
  int hq = g & 3;                       // head pair hq*2, hq*2+1
  int chunk = pblk >> 3;                // 0..1023
  int l = chunk * 4 + w;                // this wave's query
  int t31 = lane & 31;
  int half = lane >> 5;

  const float4* qp =
      (const float4*)(Q + ((size_t)(b * L_ + l) * H_ + hq * 2) * D_);
  float4 qv = qp[t31];

  int s = lane < S_ ? lane : S_ - 1;
  int idxall = idxs[l * S_ + s];

  float vmax = -FLT_MAX, vsum = 0.f;
  #pragma unroll
  for (int c = 0; c < 3; ++c) {
    int kidx[6];
    #pragma unroll
    for (int jj = 0; jj < 6; ++jj)
      kidx[jj] = __shfl(idxall, (c * 6 + jj) * 2 + half, 64);
    float4 kv[6];
    #pragma unroll
    for (int jj = 0; jj < 6; ++jj)
      kv[jj] = ((const float4*)(K +
          ((size_t)(b * L_ + kidx[jj]) * H_ + hq * 2) * D_))[t31];
    #pragma unroll
    for (int jj = 0; jj < 6; ++jj) {
      float p = qv.x * kv[jj].x;
      p = fmaf(qv.y, kv[jj].y, p);
      p = fmaf(qv.z, kv[jj].z, p);
      p = fmaf(qv.w, kv[jj].w, p);
      p += __shfl_xor(p, 1, 64);
      p += __shfl_xor(p, 2, 64);
      p += __shfl_xor(p, 4, 64);
      p += __shfl_xor(p, 8, 64);
      vmax = fmaxf(vmax, p);
      vsum += p;
    }
  }
  {
    int kidx[5];
    #pragma unroll
    for (int jj = 0; jj < 5; ++jj) {
      int s2 = (18 + jj) * 2 + half;          // 36..45
      kidx[jj] = __shfl(idxall, s2 > 44 ? 44 : s2, 64);
    }
    float4 kv[5];
    #pragma unroll
    for (int jj = 0; jj < 5; ++jj)
      kv[jj] = ((const float4*)(K +
          ((size_t)(b * L_ + kidx[jj]) * H_ + hq * 2) * D_))[t31];
    #pragma unroll
    for (int jj = 0; jj < 5; ++jj) {
      float p = qv.x * kv[jj].x;
      p = fmaf(qv.y, kv[jj].y, p);
      p = fmaf(qv.z, kv[jj].z, p);
      p = fmaf(qv.w, kv[jj].w, p);
      p += __shfl_xor(p, 1, 64);
      p += __shfl_xor(p, 2, 64);
      p += __shfl_xor(p, 4, 64);
      p += __shfl_xor(p, 8, 64);
      bool dup = (jj == 4) && (half == 1);    // sample 45 -> clamped dup
      vmax = fmaxf(vmax, p);
      if (!dup) vsum += p;
    }
  }
  vmax = fmaxf(vmax, __shfl_xor(vmax, 32, 64));
  vsum += __shfl_xor(vsum, 32, 64);
  if ((lane & 15) == 0 && half == 0) {
    int h = hq * 2 + (lane >> 4);
    M[(size_t)(b * H_ + h) * L_ + l] = vmax - vsum * (1.0f / L_);
  }
}

// ================= kB: top-45 per (b,h) + csum_scan (R12-proven) ==============
__global__ __launch_bounds__(256) void kB(
    const float* __restrict__ M, int* __restrict__ mtop, float* __restrict__ cs)
{
  int blk = blockIdx.x;
  int tid = threadIdx.x;
  if (blk >= 32) {
    int g = (blk - 32) * 256 + tid;    // 2048 threads total
    int bh = g >> 6, d = g & 63;
    float v[64];
    #pragma unroll
    for (int c = 0; c < 64; ++c) v[c] = cs[((size_t)bh * 64 + c) * D_ + d];
    float run = 0.f;
    #pragma unroll
    for (int c = 0; c < 64; ++c) {
      float a = v[c];
      cs[((size_t)bh * 64 + c) * D_ + d] = run;
      run += a;
    }
    return;
  }
  __shared__ unsigned long long cand[4][S_];
  int bh = blk;
  int w = tid >> 6, lane = tid & 63;
  const float* Mp = M + (size_t)bh * L_;
  unsigned long long key[16];
  #pragma unroll
  for (int j = 0; j < 16; ++j) {
    int gi = w * 1024 + j * 64 + lane;
    key[j] = ((unsigned long long)ordf(Mp[gi]) << 32) | (unsigned)(~gi);
  }
  for (int it = 0; it < S_; ++it) {
    unsigned long long loc = key[0];
    #pragma unroll
    for (int j = 1; j < 16; ++j) loc = key[j] > loc ? key[j] : loc;
    unsigned long long best = loc;
    #pragma unroll
    for (int m = 32; m >= 1; m >>= 1) {
      unsigned long long o = __shfl_xor(best, m, 64);
      best = o > best ? o : best;
    }
    if (loc == best) {
      #pragma unroll
      for (int j = 0; j < 16; ++j) if (key[j] == best) key[j] = 0ull;
    }
    if (lane == 0) cand[w][it] = best;
  }
  __syncthreads();
  if (w == 0) {
    unsigned long long k2[3];
    #pragma unroll
    for (int j = 0; j < 3; ++j) {
      int c = j * 64 + lane;
      k2[j] = (c < 4 * S_) ? cand[c / S_][c % S_] : 0ull;
    }
    for (int it = 0; it < S_; ++it) {
      unsigned long long loc = k2[0];
      loc = k2[1] > loc ? k2[1] : loc;
      loc = k2[2] > loc ? k2[2] : loc;
      unsigned long long best = loc;
      #pragma unroll
      for (int m = 32; m >= 1; m >>= 1) {
        unsigned long long o = __shfl_xor(best, m, 64);
        best = o > best ? o : best;
      }
      if (loc == best) {
        #pragma unroll
        for (int j = 0; j < 3; ++j) if (k2[j] == best) k2[j] = 0ull;
      }
      if (lane == 0) mtop[bh * S_ + it] = (int)(~(unsigned)(best & 0xFFFFFFFFu));
    }
  }
}

// ================= kATT: MFMA attention partials (R12-proven, KCH=256) ========
__global__ __launch_bounds__(256) void kATT(
    const float* __restrict__ Q, const float* __restrict__ K,
    const float* __restrict__ V, const int* __restrict__ mtop,
    float* __restrict__ lpart, float* __restrict__ updp)
{
  __shared__ __align__(16) ushort Ks[256 * 64];   // 32 KB; reused as Vt[64][256]
  __shared__ __align__(16) ushort Qs[48 * 64];    // 6 KB
  __shared__ __align__(16) ushort Ps[48 * 256];   // 24 KB
  __shared__ float lred[4][48];
  __shared__ int   cut[48];

  int blk = blockIdx.x;
  int kc = blk >> 5;
  int r5 = blk & 31;
  int bh = ((r5 & 7) << 2) | (r5 >> 3);   // blk%8 == bh>>2 -> XCD pin
  int b = bh >> 3, h = bh & 7;
  int tid = threadIdx.x;
  int w = tid >> 6, lane = tid & 63;
  int l15 = lane & 15, l4 = lane >> 4;

  if (tid < 48) cut[tid] = (tid < S_) ? mtop[bh * S_ + tid] : -1;
  __syncthreads();

  {
    const float4* kp =
        (const float4*)(K + ((size_t)(b * L_ + kc * KCH_ + tid) * H_ + h) * D_);
    #pragma unroll
    for (int c = 0; c < 8; ++c) {
      float4 a = kp[2 * c], bb = kp[2 * c + 1];
      uint4 pk;
      pk.x = f2bf(a.x) | ((unsigned)f2bf(a.y) << 16);
      pk.y = f2bf(a.z) | ((unsigned)f2bf(a.w) << 16);
      pk.z = f2bf(bb.x) | ((unsigned)f2bf(bb.y) << 16);
      pk.w = f2bf(bb.z) | ((unsigned)f2bf(bb.w) << 16);
      *(uint4*)&Ks[swz_us(tid, c * 16, 128, 7)] = pk;
    }
  }
  for (int i = tid; i < 48 * 8; i += 256) {
    int row = i >> 3, c = i & 7;
    uint4 pk = make_uint4(0, 0, 0, 0);
    if (row < S_) {
      const float4* qp =
          (const float4*)(Q + ((size_t)(b * L_ + cut[row]) * H_ + h) * D_);
      float4 a = qp[2 * c], bb = qp[2 * c + 1];
      pk.x = f2bf(a.x) | ((unsigned)f2bf(a.y) << 16);
      pk.y = f2bf(a.z) | ((unsigned)f2bf(a.w) << 16);
      pk.z = f2bf(bb.x) | ((unsigned)f2bf(bb.y) << 16);
      pk.w = f2bf(bb.z) | ((unsigned)f2bf(bb.w) << 16);
    }
    *(uint4*)&Qs[swz_us(row, c * 16, 128, 7)] = pk;
  }
  __syncthreads();

  float4v accS[3][4];
  #pragma unroll
  for (int mt = 0; mt < 3; ++mt)
    #pragma unroll
    for (int nt = 0; nt < 4; ++nt)
      accS[mt][nt] = (float4v){0.f, 0.f, 0.f, 0.f};
  #pragma unroll
  for (int ks = 0; ks < 2; ++ks) {
    short8 afr[3];
    #pragma unroll
    for (int mt = 0; mt < 3; ++mt)
      afr[mt] = *(const short8*)&Qs[swz_us(mt * 16 + l15, ks * 64 + l4 * 16, 128, 7)];
    #pragma unroll
    for (int nt = 0; nt < 4; ++nt) {
      short8 bfr = *(const short8*)
          &Ks[swz_us(w * 64 + nt * 16 + l15, ks * 64 + l4 * 16, 128, 7)];
      #pragma unroll
      for (int mt = 0; mt < 3; ++mt)
        accS[mt][nt] = __builtin_amdgcn_mfma_f32_16x16x32_bf16(
            afr[mt], bfr, accS[mt][nt], 0, 0, 0);
    }
  }

  #pragma unroll
  for (int mt = 0; mt < 3; ++mt) {
    #pragma unroll
    for (int j = 0; j < 4; ++j) {
      int row = mt * 16 + l4 * 4 + j;
      int ct = cut[row];
      float rs = 0.f;
      #pragma unroll
      for (int nt = 0; nt < 4; ++nt) {
        int col = w * 64 + nt * 16 + l15;
        int kg = kc * KCH_ + col;
        float e = (kg <= ct) ? __expf(accS[mt][nt][j] * SCALE) : 0.f;
        rs += e;
        Ps[swz_us(row, col * 2, 512, 15)] = f2bf(e);
      }
      rs += __shfl_xor(rs, 1, 64);
      rs += __shfl_xor(rs, 2, 64);
      rs += __shfl_xor(rs, 4, 64);
      rs += __shfl_xor(rs, 8, 64);
      if (l15 == 0) lred[w][row] = rs;
    }
  }
  __syncthreads();

  if (tid < S_)
    lpart[((size_t)(bh * KC_ + kc)) * S_ + tid] =
        lred[0][tid] + lred[1][tid] + lred[2][tid] + lred[3][tid];

  {
    const float4* vp =
        (const float4*)(V + ((size_t)(b * L_ + kc * KCH_ + tid) * H_ + h) * D_);
    #pragma unroll
    for (int c = 0; c < 16; ++c) {
      float4 v = vp[c];
      int d0 = c * 4;
      Ks[swz_us(d0 + 0, tid * 2, 512, 15)] = f2bf(v.x);
      Ks[swz_us(d0 + 1, tid * 2, 512, 15)] = f2bf(v.y);
      Ks[swz_us(d0 + 2, tid * 2, 512, 15)] = f2bf(v.z);
      Ks[swz_us(d0 + 3, tid * 2, 512, 15)] = f2bf(v.w);
    }
  }
  __syncthreads();

  float4v accU[3];
  #pragma unroll
  for (int i = 0; i < 3; ++i) accU[i] = (float4v){0.f, 0.f, 0.f, 0.f};
  #pragma unroll
  for (int ks = 0; ks < 8; ++ks) {
    #pragma unroll
    for (int i = 0; i < 3; ++i) {
      int pi = w * 3 + i, mt = pi >> 2, nt = pi & 3;
      short8 afr = *(const short8*)
          &Ps[swz_us(mt * 16 + l15, ks * 64 + l4 * 16, 512, 15)];
      short8 bfr = *(const short8*)
          &Ks[swz_us(nt * 16 + l15, ks * 64 + l4 * 16, 512, 15)];
      accU[i] = __builtin_amdgcn_mfma_f32_16x16x32_bf16(afr, bfr, accU[i], 0, 0, 0);
    }
  }
  float* up = updp + ((size_t)(bh * KC_ + kc)) * (S_ * D_);
  #pragma unroll
  for (int i = 0; i < 3; ++i) {
    int pi = w * 3 + i, mt = pi >> 2, nt = pi & 3;
    #pragma unroll
    for (int j = 0; j < 4; ++j) {
      int row = mt * 16 + l4 * 4 + j;
      if (row < S_) up[row * D_ + nt * 16 + l15] = accU[i][j];
    }
  }
}

// ================= kWD: csum_write (skip scatter rows) + finalize (R12) =======
__global__ __launch_bounds__(256) void kWD(
    const float* __restrict__ V, const float* __restrict__ cs,
    const float* __restrict__ lpart, const float* __restrict__ updp,
    const int* __restrict__ mtop, float* __restrict__ out)
{
  int blk = blockIdx.x;
  int tid = threadIdx.x;

  if (blk >= 512) {
    // ---- finalize ----
    __shared__ float linv[S_];
    __shared__ int   mt[S_];
    int bh = blk - 512;
    if (tid < S_) {
      float l = 0.f;
      for (int kc = 0; kc < KC_; ++kc) l += lpart[(size_t)(bh * KC_ + kc) * S_ + tid];
      linv[tid] = 1.0f / l;
      mt[tid] = mtop[bh * S_ + tid];
    }
    __syncthreads();
    for (int i = tid; i < S_ * D_; i += 256) {
      int r = i >> 6, d = i & 63;
      float u = 0.f;
      for (int kc = 0; kc < KC_; ++kc)
        u += updp[((size_t)(bh * KC_ + kc)) * (S_ * D_) + i];
      out[((size_t)bh * L_ + mt[r]) * D_ + d] = u * linv[r];
    }
    return;
  }

  // ---- csum_write with scatter-row skip ----
  __shared__ unsigned bits[8];   // 256-bit bitmap for this block's row window
  int bh = blk >> 4, cg2 = blk & 15;
  int base = cg2 * 256;
  if (tid < 8) bits[tid] = 0u;
  __syncthreads();
  if (tid < S_) {
    int r = mtop[bh * S_ + tid] - base;
    if ((unsigned)r < 256u) atomicOr(&bits[r >> 5], 1u << (r & 31));
  }
  __syncthreads();

  int b = bh >> 3, h = bh & 7;
  int w = tid >> 6, lane = tid & 63;
  int t = lane & 15, rg = lane >> 4;
  int c = cg2 * 4 + w;
  int l0 = c * 64;
  const float4* V4 = (const float4*)V;
  float4* O4 = (float4*)out;
  float4 carry = ((const float4*)cs)[((size_t)bh * 64 + c) * 16 + t];
  for (int step = 0; step < 16; ++step) {
    int l = l0 + step * 4 + rg;
    float4 v = V4[((size_t)(b * L_ + l) * H_ + h) * 16 + t];
    float4 u;
    u.x = __shfl_up(v.x, 16, 64); u.y = __shfl_up(v.y, 16, 64);
    u.z = __shfl_up(v.z, 16, 64); u.w = __shfl_up(v.w, 16, 64);
    if (rg >= 1) { v.x += u.x; v.y += u.y; v.z += u.z; v.w += u.w; }
    u.x = __shfl_up(v.x, 32, 64); u.y = __shfl_up(v.y, 32, 64);
    u.z = __shfl_up(v.z, 32, 64); u.w = __shfl_up(v.w, 32, 64);
    if (rg >= 2) { v.x += u.x; v.y += u.y; v.z += u.z; v.w += u.w; }
    int wl = l - base;
    if (!((bits[wl >> 5] >> (wl & 31)) & 1u)) {
      float4 o;
      o.x = carry.x + v.x; o.y = carry.y + v.y;
      o.z = carry.z + v.z; o.w = carry.w + v.w;
      O4[((size_t)bh * L_ + l) * 16 + t] = o;
    }
    carry.x += __shfl(v.x, 48 + t, 64); carry.y += __shfl(v.y, 48 + t, 64);
    carry.z += __shfl(v.z, 48 + t, 64); carry.w += __shfl(v.w, 48 + t, 64);
  }
}

extern "C" void kernel_launch(void* const* d_in, const int* in_sizes, int n_in,
                              void* d_out, int out_size, void* d_ws, size_t ws_size,
                              hipStream_t stream) {
  const float* Q = (const float*)d_in[0];
  const float* K = (const float*)d_in[1];
  const float* V = (const float*)d_in[2];
  const int*   I = (const int*)d_in[3];
  float* out = (float*)d_out;
  float* ws = (float*)d_ws;

  float* M     = ws;                       // 131072 floats
  float* cs    = ws + 131072;              // 131072 floats
  float* lpart = ws + 262144;              // 32*16*45 = 23040 floats
  float* updp  = ws + 262144 + 23040;      // 32*16*45*64 = 1474560 floats
  int*   mtop  = (int*)(ws + 262144 + 23040 + 1474560);   // 1440 ints

  kA<<<128 * 136, 256, 0, stream>>>(Q, K, V, I, M, cs);
  kB<<<40, 256, 0, stream>>>(M, mtop, cs);
  kATT<<<B_ * H_ * KC_, 256, 0, stream>>>(Q, K, V, mtop, lpart, updp);
  kWD<<<544, 256, 0, stream>>>(V, cs, lpart, updp, mtop, out);
}